// Round 1
// baseline (546.009 us; speedup 1.0000x reference)
//
#include <hip/hip_runtime.h>

typedef __attribute__((ext_vector_type(8))) short short8;
typedef __attribute__((ext_vector_type(4))) float f32x4;

static __device__ __forceinline__ float bf2f(unsigned short u) {
    unsigned int x = ((unsigned int)u) << 16;
    union { unsigned int i; float f; } c; c.i = x; return c.f;
}
static __device__ __forceinline__ unsigned short f2bf(float f) {
    union { float f; unsigned int i; } c; c.f = f;
    unsigned int x = c.i;
    unsigned int r = (x + 0x7FFFu + ((x >> 16) & 1u)) >> 16;
    return (unsigned short)r;
}

// ---------------- prepack W [Cout=128][Cin][7] fp32 -> fragment-linear bf16 ----------------
// Wp[( (s*8 + f)*64 + lane )*8 + j] = W[o = f*16+(lane&15)][c = kk%Cin][t = kk/Cin],
// kk = s*32 + 8*(lane>>4) + j
__global__ void prepack_w(const float* __restrict__ W, unsigned short* __restrict__ Wp,
                          int Cin, int S) {
    int tid = blockIdx.x * blockDim.x + threadIdx.x;
    if (tid >= S * 512) return;
    int lane = tid & 63;
    int f = (tid >> 6) & 7;
    int s = tid >> 9;
    int o = f * 16 + (lane & 15);
    int kbase = s * 32 + 8 * (lane >> 4);
    unsigned short* dst = Wp + (size_t)tid * 8;
#pragma unroll
    for (int j = 0; j < 8; ++j) {
        int kk = kbase + j;
        int t = kk / Cin;
        int c = kk - t * Cin;
        dst[j] = f2bf(W[((size_t)o * Cin + c) * 7 + t]);
    }
}

// ---------------- transpose fp32 [B][C][N] -> bf16 [B][N][ldo] at column offset ----------------
__global__ void transpose_cast(const float* __restrict__ in, unsigned short* __restrict__ out,
                               int C, int N, int ldo, int coff) {
    __shared__ float tile[32][33];
    int b = blockIdx.z;
    int n0 = blockIdx.x * 32;
    int c0 = blockIdx.y * 32;
    const float* inb = in + (size_t)b * C * N;
    unsigned short* outb = out + (size_t)b * N * ldo;
    int tx = threadIdx.x, ty = threadIdx.y;
#pragma unroll
    for (int i = 0; i < 32; i += 8) {
        int c = c0 + ty + i, n = n0 + tx;
        float v = 0.f;
        if (n < N) v = inb[(size_t)c * N + n];
        tile[ty + i][tx] = v;
    }
    __syncthreads();
#pragma unroll
    for (int i = 0; i < 32; i += 8) {
        int n = n0 + ty + i, c = c0 + tx;
        if (n < N) outb[(size_t)n * ldo + coff + c] = f2bf(tile[tx][ty + i]);
    }
}

// ---------------- gather-conv via MFMA ----------------
// src: bf16 [B][N][CS]; out: bf16 [B][N][LD] (+coff), 128 out channels, bias fp32
// A (M=16 points x K=32) = gathered features, B (K=32 x N=16 couts) = prepacked W
template<int CS, int S, int LD>
__global__ __launch_bounds__(256, 2) void conv_mfma(
    const unsigned short* __restrict__ src,
    const int* __restrict__ nbrs,
    const unsigned short* __restrict__ Wp,
    const float* __restrict__ bias,
    unsigned short* __restrict__ dst,
    int N, int coff)
{
    const int lane = threadIdx.x & 63;
    const int wid  = threadIdx.x >> 6;
    const int b    = blockIdx.y;
    const int p_base = blockIdx.x * 128 + wid * 32;
    const int l15 = lane & 15;
    const int ks  = lane >> 4;

    const unsigned short* srcb = src + (size_t)b * N * CS;

    int idx0[7], idx1[7];
    {
        int p0 = p_base + l15;        int pe0 = p0 < N ? p0 : N - 1;
        int p1 = p_base + 16 + l15;   int pe1 = p1 < N ? p1 : N - 1;
        idx0[0] = pe0; idx1[0] = pe1;
        const int* nb0 = nbrs + ((size_t)b * N + pe0) * 6;
        const int* nb1 = nbrs + ((size_t)b * N + pe1) * 6;
#pragma unroll
        for (int t = 1; t < 7; ++t) { idx0[t] = nb0[t - 1]; idx1[t] = nb1[t - 1]; }
    }

    float bias_v[8];
#pragma unroll
    for (int f = 0; f < 8; ++f) bias_v[f] = bias[f * 16 + l15];

    f32x4 acc[2][8];
#pragma unroll
    for (int pf = 0; pf < 2; ++pf)
#pragma unroll
        for (int f = 0; f < 8; ++f) acc[pf][f] = (f32x4){0.f, 0.f, 0.f, 0.f};

    const int SPT = CS / 32;  // K-steps per tap
#pragma unroll
    for (int t = 0; t < 7; ++t) {
        const unsigned short* row0 = srcb + (size_t)idx0[t] * CS + 8 * ks;
        const unsigned short* row1 = srcb + (size_t)idx1[t] * CS + 8 * ks;
#pragma unroll 2
        for (int s2 = 0; s2 < SPT; ++s2) {
            const int s = t * SPT + s2;
            short8 a0 = *reinterpret_cast<const short8*>(row0 + s2 * 32);
            short8 a1 = *reinterpret_cast<const short8*>(row1 + s2 * 32);
            const short8* wbase = reinterpret_cast<const short8*>(Wp) + ((size_t)s * 512 + lane);
#pragma unroll
            for (int f = 0; f < 8; ++f) {
                short8 bf = wbase[f * 64];
                acc[0][f] = __builtin_amdgcn_mfma_f32_16x16x32_bf16(a0, bf, acc[0][f], 0, 0, 0);
                acc[1][f] = __builtin_amdgcn_mfma_f32_16x16x32_bf16(a1, bf, acc[1][f], 0, 0, 0);
            }
        }
    }

    unsigned short* dstb = dst + (size_t)b * N * LD + coff;
#pragma unroll
    for (int pf = 0; pf < 2; ++pf) {
#pragma unroll
        for (int r = 0; r < 4; ++r) {
            int p = p_base + pf * 16 + ks * 4 + r;
            if (p < N) {
#pragma unroll
                for (int f = 0; f < 8; ++f) {
                    dstb[(size_t)p * LD + f * 16 + l15] = f2bf(acc[pf][f][r] + bias_v[f]);
                }
            }
        }
    }
}

// ---------------- instance-norm stats: partial sums ----------------
__global__ void stats_partial(const unsigned short* __restrict__ x, float* __restrict__ part,
                              int N, int NB) {
    int b = blockIdx.y, blk = blockIdx.x;
    int c = threadIdx.x & 127, rg = threadIdx.x >> 7;
    int rows = (N + NB - 1) / NB;
    int n0 = blk * rows;
    int n1 = n0 + rows; if (n1 > N) n1 = N;
    const unsigned short* xb = x + (size_t)b * N * 128;
    float s = 0.f, sq = 0.f;
    for (int n = n0 + rg; n < n1; n += 2) {
        float v = bf2f(xb[(size_t)n * 128 + c]);
        s += v; sq += v * v;
    }
    __shared__ float sh[2][2][128];
    sh[rg][0][c] = s; sh[rg][1][c] = sq;
    __syncthreads();
    if (rg == 0) {
        s  += sh[1][0][c];
        sq += sh[1][1][c];
        float2* o = (float2*)part;
        o[((size_t)b * NB + blk) * 128 + c] = make_float2(s, sq);
    }
}

__global__ void stats_final(const float* __restrict__ part, float2* __restrict__ stats,
                            int N, int NB) {
    int b = blockIdx.x, c = threadIdx.x;
    const float2* p = (const float2*)part + (size_t)b * NB * 128 + c;
    float s = 0.f, sq = 0.f;
    for (int i = 0; i < NB; ++i) { float2 v = p[(size_t)i * 128]; s += v.x; sq += v.y; }
    float mu = s / N;
    float var = sq / N - mu * mu;
    stats[b * 128 + c] = make_float2(mu, rsqrtf(var + 1e-5f));
}

// ---------------- normalize: y = (x - mu) * rstd (bf16 -> bf16) ----------------
__global__ void normalize_k(const unsigned short* __restrict__ x, const float2* __restrict__ stats,
                            unsigned short* __restrict__ y, int N, int total8) {
    int e = blockIdx.x * blockDim.x + threadIdx.x;
    if (e >= total8) return;
    size_t base = (size_t)e * 8;
    int c0 = (int)(base & 127);
    int b = (int)(base / ((size_t)N * 128));
    short8 in = *reinterpret_cast<const short8*>(x + base);
    short8 out;
#pragma unroll
    for (int j = 0; j < 8; ++j) {
        float2 st = stats[b * 128 + c0 + j];
        float v = (bf2f((unsigned short)in[j]) - st.x) * st.y;
        out[j] = (short)f2bf(v);
    }
    *reinterpret_cast<short8*>(y + base) = out;
}

// ---------------- final: out[b][o][n] = (z - mu2)*rstd2 + x1n, fp32 transposed ----------------
__global__ void final_k(const unsigned short* __restrict__ z, const unsigned short* __restrict__ x1n,
                        const float2* __restrict__ stats2, float* __restrict__ out, int N) {
    __shared__ float tile[32][33];
    int b = blockIdx.z;
    int n0 = blockIdx.x * 32, o0 = blockIdx.y * 32;
    int tx = threadIdx.x, ty = threadIdx.y;
    const unsigned short* zb = z  + (size_t)b * N * 128;
    const unsigned short* xb = x1n + (size_t)b * N * 128;
    float2 st = stats2[b * 128 + o0 + tx];
#pragma unroll
    for (int i = 0; i < 32; i += 8) {
        int n = n0 + ty + i;
        float v = 0.f;
        if (n < N) {
            float zv = bf2f(zb[(size_t)n * 128 + o0 + tx]);
            float xv = bf2f(xb[(size_t)n * 128 + o0 + tx]);
            v = (zv - st.x) * st.y + xv;
        }
        tile[ty + i][tx] = v;
    }
    __syncthreads();
    float* ob = out + (size_t)b * 128 * N;
#pragma unroll
    for (int i = 0; i < 32; i += 8) {
        int o = o0 + ty + i, n = n0 + tx;
        if (n < N) ob[(size_t)o * N + n] = tile[tx][ty + i];
    }
}

extern "C" void kernel_launch(void* const* d_in, const int* in_sizes, int n_in,
                              void* d_out, int out_size, void* d_ws, size_t ws_size,
                              hipStream_t stream) {
    const float* from_up   = (const float*)d_in[0];  // [2,256,30000]
    const float* from_down = (const float*)d_in[1];  // [2,128,30000]
    const int*   neighbors = (const int*)d_in[2];    // [2,30000,6]
    const float* W_up = (const float*)d_in[3];
    const float* b_up = (const float*)d_in[4];
    const float* W_1  = (const float*)d_in[5];
    const float* b_1  = (const float*)d_in[6];
    const float* W_2  = (const float*)d_in[7];
    const float* b_2  = (const float*)d_in[8];
    float* out = (float*)d_out;

    const int B = 2, N = 30000;
    const int S1 = 56, S3 = 28;  // K-steps: 1792/32, 896/32

    char* ws = (char*)d_ws;
    size_t off = 0;
    auto alloc = [&](size_t bytes) {
        char* p = ws + off;
        off += (bytes + 255) & ~(size_t)255;
        return p;
    };
    unsigned short* upT   = (unsigned short*)alloc((size_t)B * N * 256 * 2);
    unsigned short* catT  = (unsigned short*)alloc((size_t)B * N * 256 * 2);
    unsigned short* x1    = (unsigned short*)alloc((size_t)B * N * 128 * 2);
    unsigned short* x1n   = (unsigned short*)alloc((size_t)B * N * 128 * 2);
    unsigned short* Wp0   = (unsigned short*)alloc((size_t)S1 * 512 * 8 * 2);
    unsigned short* Wp1   = (unsigned short*)alloc((size_t)S1 * 512 * 8 * 2);
    unsigned short* Wp2   = (unsigned short*)alloc((size_t)S3 * 512 * 8 * 2);
    const int NB = 32;
    float* part   = (float*)alloc((size_t)B * NB * 128 * 2 * 4);
    float2* stats1 = (float2*)alloc((size_t)B * 128 * 8);
    float2* stats2 = (float2*)alloc((size_t)B * 128 * 8);
    unsigned short* zbuf = upT;  // reuse (upT dead after conv1)

    // prepack weights
    prepack_w<<<(S1 * 512 + 255) / 256, 256, 0, stream>>>(W_up, Wp0, 256, S1);
    prepack_w<<<(S1 * 512 + 255) / 256, 256, 0, stream>>>(W_1,  Wp1, 256, S1);
    prepack_w<<<(S3 * 512 + 255) / 256, 256, 0, stream>>>(W_2,  Wp2, 128, S3);

    // transpose inputs to [B][N][C] bf16
    dim3 tb(32, 8);
    transpose_cast<<<dim3((N + 31) / 32, 256 / 32, B), tb, 0, stream>>>(from_up, upT, 256, N, 256, 0);
    transpose_cast<<<dim3((N + 31) / 32, 128 / 32, B), tb, 0, stream>>>(from_down, catT, 128, N, 256, 128);

    dim3 cgrid((N + 127) / 128, B);
    // conv1: upT (Cin=256) -> catT[:, 0:128]
    conv_mfma<256, S1, 256><<<cgrid, 256, 0, stream>>>(upT, neighbors, Wp0, b_up, catT, N, 0);
    // conv2: catT (Cin=256) -> x1
    conv_mfma<256, S1, 128><<<cgrid, 256, 0, stream>>>(catT, neighbors, Wp1, b_1, x1, N, 0);

    // instance norm 1
    stats_partial<<<dim3(NB, B), 256, 0, stream>>>(x1, part, N, NB);
    stats_final<<<B, 128, 0, stream>>>(part, stats1, N, NB);
    int total8 = B * N * 128 / 8;
    normalize_k<<<(total8 + 255) / 256, 256, 0, stream>>>(x1, stats1, x1n, N, total8);

    // conv3: x1n (Cin=128) -> zbuf
    conv_mfma<128, S3, 128><<<cgrid, 256, 0, stream>>>(x1n, neighbors, Wp2, b_2, zbuf, N, 0);

    // instance norm 2 stats
    stats_partial<<<dim3(NB, B), 256, 0, stream>>>(zbuf, part, N, NB);
    stats_final<<<B, 128, 0, stream>>>(part, stats2, N, NB);

    // final: normalize z, add residual, transpose to [B][128][N] fp32
    final_k<<<dim3((N + 31) / 32, 4, B), tb, 0, stream>>>(zbuf, x1n, stats2, out, N);
}

// Round 2
// 439.181 us; speedup vs baseline: 1.2432x; 1.2432x over previous
//
#include <hip/hip_runtime.h>

typedef __attribute__((ext_vector_type(8))) short short8;
typedef __attribute__((ext_vector_type(4))) float f32x4;

static __device__ __forceinline__ float bf2f(unsigned short u) {
    unsigned int x = ((unsigned int)u) << 16;
    union { unsigned int i; float f; } c; c.i = x; return c.f;
}
static __device__ __forceinline__ unsigned short f2bf(float f) {
    union { float f; unsigned int i; } c; c.f = f;
    unsigned int x = c.i;
    unsigned int r = (x + 0x7FFFu + ((x >> 16) & 1u)) >> 16;
    return (unsigned short)r;
}

// ---------------- prepack W [Cout=128][Cin][7] fp32 -> fragment-linear bf16 ----------------
// Wp[( (s*8 + f)*64 + lane )*8 + j] = W[o = f*16+(lane&15)][c = kk%Cin][t = kk/Cin],
// kk = s*32 + 8*(lane>>4) + j
__global__ void prepack_w(const float* __restrict__ W, unsigned short* __restrict__ Wp,
                          int Cin, int S) {
    int tid = blockIdx.x * blockDim.x + threadIdx.x;
    if (tid >= S * 512) return;
    int lane = tid & 63;
    int f = (tid >> 6) & 7;
    int s = tid >> 9;
    int o = f * 16 + (lane & 15);
    int kbase = s * 32 + 8 * (lane >> 4);
    unsigned short* dst = Wp + (size_t)tid * 8;
#pragma unroll
    for (int j = 0; j < 8; ++j) {
        int kk = kbase + j;
        int t = kk / Cin;
        int c = kk - t * Cin;
        dst[j] = f2bf(W[((size_t)o * Cin + c) * 7 + t]);
    }
}

// Same but scales W[o][c][t] by rstd[b][c] (norm folded into conv3), one copy per batch.
__global__ void prepack_w_scaled(const float* __restrict__ W, const float2* __restrict__ stats,
                                 unsigned short* __restrict__ Wp, int Cin, int S) {
    int tid = blockIdx.x * blockDim.x + threadIdx.x;
    if (tid >= 2 * S * 512) return;
    int b = tid / (S * 512);
    int rem = tid - b * S * 512;
    int lane = rem & 63;
    int f = (rem >> 6) & 7;
    int s = rem >> 9;
    int o = f * 16 + (lane & 15);
    int kbase = s * 32 + 8 * (lane >> 4);
    unsigned short* dst = Wp + (size_t)tid * 8;
#pragma unroll
    for (int j = 0; j < 8; ++j) {
        int kk = kbase + j;
        int t = kk / Cin;
        int c = kk - t * Cin;
        float scale = stats[b * 128 + c].y;
        dst[j] = f2bf(W[((size_t)o * Cin + c) * 7 + t] * scale);
    }
}

// b2'[b][o] = b2[o] - sum_{c,t} W2[o][c][t] * rstd[b][c] * mu[b][c]
__global__ void fold_bias2(const float* __restrict__ W2, const float* __restrict__ b2,
                           const float2* __restrict__ stats, float* __restrict__ b2out) {
    int b = blockIdx.x, o = threadIdx.x;
    float sum = 0.f;
    for (int c = 0; c < 128; ++c) {
        float2 st = stats[b * 128 + c];
        float sm = st.x * st.y;
        float ws = 0.f;
#pragma unroll
        for (int t = 0; t < 7; ++t) ws += W2[((size_t)o * 128 + c) * 7 + t];
        sum += ws * sm;
    }
    b2out[b * 128 + o] = b2[o] - sum;
}

// ---------------- transpose fp32 [B][C][N] -> bf16 [B][N][ldo] at column offset ----------------
__global__ void transpose_cast(const float* __restrict__ in, unsigned short* __restrict__ out,
                               int C, int N, int ldo, int coff) {
    __shared__ float tile[32][33];
    int b = blockIdx.z;
    int n0 = blockIdx.x * 32;
    int c0 = blockIdx.y * 32;
    const float* inb = in + (size_t)b * C * N;
    unsigned short* outb = out + (size_t)b * N * ldo;
    int tx = threadIdx.x, ty = threadIdx.y;
#pragma unroll
    for (int i = 0; i < 32; i += 8) {
        int c = c0 + ty + i, n = n0 + tx;
        float v = 0.f;
        if (n < N) v = inb[(size_t)c * N + n];
        tile[ty + i][tx] = v;
    }
    __syncthreads();
#pragma unroll
    for (int i = 0; i < 32; i += 8) {
        int n = n0 + ty + i, c = c0 + tx;
        if (n < N) outb[(size_t)n * ldo + coff + c] = f2bf(tile[tx][ty + i]);
    }
}

// ---------------- gather-conv via MFMA, optional fused per-block stats ----------------
// src: bf16 [B][N][CS]; out: bf16 [B][N][LD] (+coff), 128 out channels, bias fp32
template<int CS, int LD, bool STATS>
__global__ __launch_bounds__(256, 2) void conv_mfma(
    const unsigned short* __restrict__ src,
    const int* __restrict__ nbrs,
    const unsigned short* __restrict__ Wp, size_t w_bstride8,
    const float* __restrict__ bias, int bias_bstride,
    unsigned short* __restrict__ dst,
    float2* __restrict__ part,
    int N, int coff)
{
    const int lane = threadIdx.x & 63;
    const int wid  = threadIdx.x >> 6;
    const int b    = blockIdx.y;
    const int p_base = blockIdx.x * 128 + wid * 32;
    const int l15 = lane & 15;
    const int ks  = lane >> 4;

    const unsigned short* srcb = src + (size_t)b * N * CS;
    const short8* wb = reinterpret_cast<const short8*>(Wp) + (size_t)b * w_bstride8;
    const float* biasb = bias + (size_t)b * bias_bstride;

    int idx0[7], idx1[7];
    {
        int p0 = p_base + l15;        int pe0 = p0 < N ? p0 : N - 1;
        int p1 = p_base + 16 + l15;   int pe1 = p1 < N ? p1 : N - 1;
        idx0[0] = pe0; idx1[0] = pe1;
        const int* nb0 = nbrs + ((size_t)b * N + pe0) * 6;
        const int* nb1 = nbrs + ((size_t)b * N + pe1) * 6;
#pragma unroll
        for (int t = 1; t < 7; ++t) { idx0[t] = nb0[t - 1]; idx1[t] = nb1[t - 1]; }
    }

    float bias_v[8];
#pragma unroll
    for (int f = 0; f < 8; ++f) bias_v[f] = biasb[f * 16 + l15];

    f32x4 acc[2][8];
#pragma unroll
    for (int pf = 0; pf < 2; ++pf)
#pragma unroll
        for (int f = 0; f < 8; ++f) acc[pf][f] = (f32x4){0.f, 0.f, 0.f, 0.f};

    const int SPT = CS / 32;  // K-steps per tap
#pragma unroll
    for (int t = 0; t < 7; ++t) {
        const unsigned short* row0 = srcb + (size_t)idx0[t] * CS + 8 * ks;
        const unsigned short* row1 = srcb + (size_t)idx1[t] * CS + 8 * ks;
#pragma unroll 2
        for (int s2 = 0; s2 < SPT; ++s2) {
            const int s = t * SPT + s2;
            short8 a0 = *reinterpret_cast<const short8*>(row0 + s2 * 32);
            short8 a1 = *reinterpret_cast<const short8*>(row1 + s2 * 32);
            const short8* wbase = wb + ((size_t)s * 512 + lane);
#pragma unroll
            for (int f = 0; f < 8; ++f) {
                short8 bfv = wbase[f * 64];
                acc[0][f] = __builtin_amdgcn_mfma_f32_16x16x32_bf16(a0, bfv, acc[0][f], 0, 0, 0);
                acc[1][f] = __builtin_amdgcn_mfma_f32_16x16x32_bf16(a1, bfv, acc[1][f], 0, 0, 0);
            }
        }
    }

    unsigned short* dstb = dst + (size_t)b * N * LD + coff;
#pragma unroll
    for (int pf = 0; pf < 2; ++pf) {
#pragma unroll
        for (int r = 0; r < 4; ++r) {
            int p = p_base + pf * 16 + ks * 4 + r;
            if (p < N) {
#pragma unroll
                for (int f = 0; f < 8; ++f) {
                    dstb[(size_t)p * LD + f * 16 + l15] = f2bf(acc[pf][f][r] + bias_v[f]);
                }
            }
        }
    }

    if constexpr (STATS) {
        float s[8], q[8];
#pragma unroll
        for (int f = 0; f < 8; ++f) { s[f] = 0.f; q[f] = 0.f; }
#pragma unroll
        for (int pf = 0; pf < 2; ++pf) {
#pragma unroll
            for (int r = 0; r < 4; ++r) {
                int p = p_base + pf * 16 + ks * 4 + r;
                if (p < N) {
#pragma unroll
                    for (int f = 0; f < 8; ++f) {
                        float v = acc[pf][f][r] + bias_v[f];
                        s[f] += v; q[f] += v * v;
                    }
                }
            }
        }
        // combine the 4 ks-groups (different points, same channels)
#pragma unroll
        for (int f = 0; f < 8; ++f) {
            s[f] += __shfl_xor(s[f], 16); s[f] += __shfl_xor(s[f], 32);
            q[f] += __shfl_xor(q[f], 16); q[f] += __shfl_xor(q[f], 32);
        }
        __shared__ float shs[4][128], shq[4][128];
        if (lane < 16) {
#pragma unroll
            for (int f = 0; f < 8; ++f) {
                shs[wid][f * 16 + l15] = s[f];
                shq[wid][f * 16 + l15] = q[f];
            }
        }
        __syncthreads();
        if (threadIdx.x < 128) {
            int c = threadIdx.x;
            float ss = shs[0][c] + shs[1][c] + shs[2][c] + shs[3][c];
            float qq = shq[0][c] + shq[1][c] + shq[2][c] + shq[3][c];
            part[((size_t)b * gridDim.x + blockIdx.x) * 128 + c] = make_float2(ss, qq);
        }
    }
}

__global__ void stats_final(const float2* __restrict__ part, float2* __restrict__ stats,
                            int N, int NB) {
    int b = blockIdx.x, c = threadIdx.x;
    const float2* p = part + (size_t)b * NB * 128 + c;
    float s = 0.f, sq = 0.f;
    for (int i = 0; i < NB; ++i) { float2 v = p[(size_t)i * 128]; s += v.x; sq += v.y; }
    float mu = s / N;
    float var = sq / N - mu * mu;
    stats[b * 128 + c] = make_float2(mu, rsqrtf(var + 1e-5f));
}

// ---------------- final: out[b][o][n] = (z-mu2)*rstd2 + (x1-mu1)*rstd1, fp32 transposed ----------------
__global__ void final_k(const unsigned short* __restrict__ z, const unsigned short* __restrict__ x1,
                        const float2* __restrict__ stats1, const float2* __restrict__ stats2,
                        float* __restrict__ out, int N) {
    __shared__ float tile[32][33];
    int b = blockIdx.z;
    int n0 = blockIdx.x * 32, o0 = blockIdx.y * 32;
    int tx = threadIdx.x, ty = threadIdx.y;
    const unsigned short* zb = z  + (size_t)b * N * 128;
    const unsigned short* xb = x1 + (size_t)b * N * 128;
    float2 st1 = stats1[b * 128 + o0 + tx];
    float2 st2 = stats2[b * 128 + o0 + tx];
#pragma unroll
    for (int i = 0; i < 32; i += 8) {
        int n = n0 + ty + i;
        float v = 0.f;
        if (n < N) {
            float zv = bf2f(zb[(size_t)n * 128 + o0 + tx]);
            float xv = bf2f(xb[(size_t)n * 128 + o0 + tx]);
            v = (zv - st2.x) * st2.y + (xv - st1.x) * st1.y;
        }
        tile[ty + i][tx] = v;
    }
    __syncthreads();
    float* ob = out + (size_t)b * 128 * N;
#pragma unroll
    for (int i = 0; i < 32; i += 8) {
        int o = o0 + ty + i, n = n0 + tx;
        if (n < N) ob[(size_t)o * N + n] = tile[tx][ty + i];
    }
}

extern "C" void kernel_launch(void* const* d_in, const int* in_sizes, int n_in,
                              void* d_out, int out_size, void* d_ws, size_t ws_size,
                              hipStream_t stream) {
    const float* from_up   = (const float*)d_in[0];  // [2,256,30000]
    const float* from_down = (const float*)d_in[1];  // [2,128,30000]
    const int*   neighbors = (const int*)d_in[2];    // [2,30000,6]
    const float* W_up = (const float*)d_in[3];
    const float* b_up = (const float*)d_in[4];
    const float* W_1  = (const float*)d_in[5];
    const float* b_1  = (const float*)d_in[6];
    const float* W_2  = (const float*)d_in[7];
    const float* b_2  = (const float*)d_in[8];
    float* out = (float*)d_out;

    const int B = 2, N = 30000;
    const int S1 = 56, S3 = 28;   // K-steps: 1792/32, 896/32
    const int NBLK = (N + 127) / 128;  // 235 conv blocks per batch

    char* ws = (char*)d_ws;
    size_t off = 0;
    auto alloc = [&](size_t bytes) {
        char* p = ws + off;
        off += (bytes + 255) & ~(size_t)255;
        return p;
    };
    unsigned short* upT   = (unsigned short*)alloc((size_t)B * N * 256 * 2);
    unsigned short* catT  = (unsigned short*)alloc((size_t)B * N * 256 * 2);
    unsigned short* x1    = (unsigned short*)alloc((size_t)B * N * 128 * 2);
    unsigned short* Wp0   = (unsigned short*)alloc((size_t)S1 * 512 * 8 * 2);
    unsigned short* Wp1   = (unsigned short*)alloc((size_t)S1 * 512 * 8 * 2);
    unsigned short* Wp2b  = (unsigned short*)alloc((size_t)B * S3 * 512 * 8 * 2);
    float*  b2fold = (float*)alloc((size_t)B * 128 * 4);
    float2* part   = (float2*)alloc((size_t)B * NBLK * 128 * 8);
    float2* stats1 = (float2*)alloc((size_t)B * 128 * 8);
    float2* stats2 = (float2*)alloc((size_t)B * 128 * 8);
    unsigned short* zbuf = upT;  // reuse (upT dead after conv1)

    // prepack static weights
    prepack_w<<<(S1 * 512 + 255) / 256, 256, 0, stream>>>(W_up, Wp0, 256, S1);
    prepack_w<<<(S1 * 512 + 255) / 256, 256, 0, stream>>>(W_1,  Wp1, 256, S1);

    // transpose inputs to [B][N][C] bf16
    dim3 tb(32, 8);
    transpose_cast<<<dim3((N + 31) / 32, 256 / 32, B), tb, 0, stream>>>(from_up, upT, 256, N, 256, 0);
    transpose_cast<<<dim3((N + 31) / 32, 128 / 32, B), tb, 0, stream>>>(from_down, catT, 128, N, 256, 128);

    dim3 cgrid(NBLK, B);
    // conv1: upT (Cin=256) -> catT[:, 0:128]
    conv_mfma<256, 256, false><<<cgrid, 256, 0, stream>>>(
        upT, neighbors, Wp0, 0, b_up, 0, catT, nullptr, N, 0);
    // conv2: catT (Cin=256) -> x1, fused stats partials
    conv_mfma<256, 128, true><<<cgrid, 256, 0, stream>>>(
        catT, neighbors, Wp1, 0, b_1, 0, x1, part, N, 0);
    stats_final<<<B, 128, 0, stream>>>((const float2*)part, stats1, N, NBLK);

    // fold norm1 into conv3's weights/bias (per batch)
    prepack_w_scaled<<<(B * S3 * 512 + 255) / 256, 256, 0, stream>>>(W_2, stats1, Wp2b, 128, S3);
    fold_bias2<<<B, 128, 0, stream>>>(W_2, b_2, stats1, b2fold);

    // conv3: x1 (Cin=128, scaled weights) -> zbuf, fused stats partials
    conv_mfma<128, 128, true><<<cgrid, 256, 0, stream>>>(
        x1, neighbors, Wp2b, (size_t)S3 * 512, b2fold, 128, zbuf, part, N, 0);
    stats_final<<<B, 128, 0, stream>>>((const float2*)part, stats2, N, NBLK);

    // final: normalize z, add recomputed x1n, transpose to [B][128][N] fp32
    final_k<<<dim3((N + 31) / 32, 4, B), tb, 0, stream>>>(zbuf, x1, stats1, stats2, out, N);
}